// Round 1
// baseline (1726.746 us; speedup 1.0000x reference)
//
#include <hip/hip_runtime.h>
#include <math.h>

#define B_    32
#define T_    512
#define WDIM_ 300
#define H_    256
#define G4_   1024            // 4*H
#define M_    (B_ * T_)       // 16384

// persistent-LSTM geometry: team = 8 WGs covering one (dir, batch-pair)
#define NCG   8               // col groups per team (32 d's each)
#define NWG   256             // 2 dirs * 16 batch-pairs * NCG
#define THR   512
#define HXN   (2 * 2 * B_ * H_)   // packets: [buf][dir][32][256]

// repeat macros -> compile-time-constant indices (SROA-safe register arrays)
#define RPT4(M, b)  M(b) M((b)+1) M((b)+2) M((b)+3)
#define RPT16(M, b) RPT4(M, b) RPT4(M, (b)+4) RPT4(M, (b)+8) RPT4(M, (b)+12)
#define RPT64(M)    RPT16(M, 0) RPT16(M, 16) RPT16(M, 32) RPT16(M, 48)

// ---------------------------------------------------------------------------
// Kernel 1: z = relu(emb[x] @ W_in + b_in)   [16384,300]@[300,256]
// ---------------------------------------------------------------------------
__global__ __launch_bounds__(256)
void k_embed_proj(const float* __restrict__ emb, const float* __restrict__ Win,
                  const float* __restrict__ bin, const int* __restrict__ x,
                  float* __restrict__ z)
{
    __shared__ float Ash[16][132];
    __shared__ float Bsh[16][132];
    __shared__ int   rows[128];

    const int tid = threadIdx.x;
    const int tx = tid & 15, ty = tid >> 4;
    const int rm = blockIdx.y * 128;
    const int cn = blockIdx.x * 128;

    if (tid < 128) rows[tid] = x[rm + tid];
    __syncthreads();

    float acc[8][8];
#pragma unroll
    for (int i = 0; i < 8; ++i)
#pragma unroll
        for (int j = 0; j < 8; ++j) acc[i][j] = 0.f;

    for (int kc = 0; kc < 19; ++kc) {
        const int k0 = kc * 16;
#pragma unroll
        for (int e = 0; e < 8; ++e) {
            const int idx = e * 256 + tid;
            const int r = idx >> 4, kk = idx & 15;
            const int k = k0 + kk;
            const int v = rows[r];
            Ash[kk][r] = (k < WDIM_) ? emb[(size_t)v * WDIM_ + k] : 0.f;
        }
#pragma unroll
        for (int e = 0; e < 8; ++e) {
            const int idx = e * 256 + tid;
            const int kk = idx >> 7, n = idx & 127;
            const int k = k0 + kk;
            Bsh[kk][n] = (k < WDIM_) ? Win[(size_t)k * H_ + cn + n] : 0.f;
        }
        __syncthreads();
#pragma unroll
        for (int kk = 0; kk < 16; ++kk) {
            float a[8], bb[8];
#pragma unroll
            for (int i = 0; i < 8; ++i) a[i] = Ash[kk][ty * 8 + i];
#pragma unroll
            for (int j = 0; j < 8; ++j) bb[j] = Bsh[kk][tx * 8 + j];
#pragma unroll
            for (int i = 0; i < 8; ++i)
#pragma unroll
                for (int j = 0; j < 8; ++j) acc[i][j] += a[i] * bb[j];
        }
        __syncthreads();
    }

#pragma unroll
    for (int i = 0; i < 8; ++i) {
        const int row = rm + ty * 8 + i;
#pragma unroll
        for (int j = 0; j < 8; ++j) {
            const int col = cn + tx * 8 + j;
            z[(size_t)row * H_ + col] = fmaxf(acc[i][j] + bin[col], 0.f);
        }
    }
}

// ---------------------------------------------------------------------------
// Kernel 2: P_d = z @ Wih_d + bl_d  (both directions via blockIdx.z)
// ---------------------------------------------------------------------------
__global__ __launch_bounds__(256)
void k_in_proj(const float* __restrict__ z,
               const float* __restrict__ Wf, const float* __restrict__ blf,
               const float* __restrict__ Wb, const float* __restrict__ blb,
               float* __restrict__ Pf, float* __restrict__ Pb)
{
    const float* W  = blockIdx.z ? Wb  : Wf;
    const float* bl = blockIdx.z ? blb : blf;
    float*       P  = blockIdx.z ? Pb  : Pf;

    __shared__ float Ash[16][132];
    __shared__ float Bsh[16][132];

    const int tid = threadIdx.x;
    const int tx = tid & 15, ty = tid >> 4;
    const int rm = blockIdx.y * 128;
    const int cn = blockIdx.x * 128;

    float acc[8][8];
#pragma unroll
    for (int i = 0; i < 8; ++i)
#pragma unroll
        for (int j = 0; j < 8; ++j) acc[i][j] = 0.f;

    for (int kc = 0; kc < 16; ++kc) {
        const int k0 = kc * 16;
#pragma unroll
        for (int e = 0; e < 8; ++e) {
            const int idx = e * 256 + tid;
            const int r = idx >> 4, kk = idx & 15;
            Ash[kk][r] = z[(size_t)(rm + r) * H_ + k0 + kk];
        }
#pragma unroll
        for (int e = 0; e < 8; ++e) {
            const int idx = e * 256 + tid;
            const int kk = idx >> 7, n = idx & 127;
            Bsh[kk][n] = W[(size_t)(k0 + kk) * G4_ + cn + n];
        }
        __syncthreads();
#pragma unroll
        for (int kk = 0; kk < 16; ++kk) {
            float a[8], bb[8];
#pragma unroll
            for (int i = 0; i < 8; ++i) a[i] = Ash[kk][ty * 8 + i];
#pragma unroll
            for (int j = 0; j < 8; ++j) bb[j] = Bsh[kk][tx * 8 + j];
#pragma unroll
            for (int i = 0; i < 8; ++i)
#pragma unroll
                for (int j = 0; j < 8; ++j) acc[i][j] += a[i] * bb[j];
        }
        __syncthreads();
    }

#pragma unroll
    for (int i = 0; i < 8; ++i) {
        const int row = rm + ty * 8 + i;
#pragma unroll
        for (int j = 0; j < 8; ++j) {
            const int col = cn + tx * 8 + j;
            P[(size_t)row * G4_ + col] = acc[i][j] + bl[col];
        }
    }
}

// ---------------------------------------------------------------------------
// Init: zero h packet buffers ({h=0, tag=0} == initial state)
// ---------------------------------------------------------------------------
__global__ void k_init(unsigned long long* __restrict__ hx)
{
    const int i = blockIdx.x * blockDim.x + threadIdx.x;
    if (i < HXN) hx[i] = 0ull;
}

// ---------------------------------------------------------------------------
// Kernel 3: persistent bidirectional LSTM recurrence, fence-free.
// WG = (dir, batch-pair bg, colgroup cg of 32 d's). Team = 8 colgroups.
//
// v2 (this round): LDS h-broadcast eliminated. Each wave owns one k-quarter
// (wave = (q, col-half)); lane l polls packets h[row][q*64+l] for both rows
// directly from L2 into its own registers, and the GEMV broadcasts h[k]
// across the wave via v_readlane -> SGPR operand of v_fmac. This removes
// 32 ds_read_b128 broadcasts + the h staging write + one barrier per step
// (the old LDS pipe was ~2000 cyc/step, the dominant per-step cost).
// zp is parity double-buffered so a single barrier per step suffices:
// any WG's publish of tag t+1 transitively requires every team WG's publish
// of tag t (each WG's waves cover all 256 dims), so zp[par] reuse at step
// s+2 is ordered after the gate-read of step s. Packet protocol unchanged.
// Accumulation order (k ascending, then q0..q3) is bitwise-identical to v1.
// ---------------------------------------------------------------------------
__global__ __launch_bounds__(THR, 2)
void k_lstm_persist(const float* __restrict__ Pf, const float* __restrict__ Pb,
                    const float* __restrict__ Whf, const float* __restrict__ Whb,
                    const int* __restrict__ lengths,
                    unsigned long long* __restrict__ hx,
                    float* __restrict__ pool)
{
    __shared__ float zp[2][4][2][128];   // [parity][ksplit][row][local col]

    const int tid = threadIdx.x;
    const int wg  = blockIdx.x;
    const int bg  = wg & 15;
    const int dir = (wg >> 4) & 1;
    const int cg  = wg >> 5;          // 0..7

    const float* P   = dir ? Pb  : Pf;
    const float* Whh = dir ? Whb : Whf;

    const int brow0 = bg * 2;
    const int len0 = lengths[brow0], len1 = lengths[brow0 + 1];
    const int tmax = max(len0, len1);

    // wave mapping: wave w = (q, col-half); lane -> one local col cl
    const int lane = tid & 63;
    const int w    = tid >> 6;
    const int q    = w >> 1;                      // k-quarter 0..3
    const int cl   = ((w & 1) << 6) | lane;       // local col 0..127
    const int g0   = cl >> 5;
    const int dd0  = cl & 31;
    const int gcol = g0 * 256 + cg * 32 + dd0;    // global gate column
    const int q64  = q * 64;

    // persistent W slice: 64 floats (constant indices only!)
    float wv[64];
    {
        const float* wp = Whh + (size_t)q64 * G4_ + gcol;
#define LOADW(k) wv[k] = wp[(size_t)(k) * G4_];
        RPT64(LOADW)
#undef LOADW
    }

    // gate mapping (tid < 64): row gr, local hidden index gd
    const int gr    = (tid >> 5) & 1;
    const int gd    = tid & 31;
    const int gbrow = brow0 + gr;
    const int glen  = gr ? len1 : len0;
    float cst = 0.f, hreg = 0.f, pacc = 0.f;

    // per-lane packet slots: this wave's quarter, both rows
    unsigned long long* slotR0 = hx + ((size_t)dir * 32 + brow0) * 256 + q64 + lane;
    unsigned long long* slotR1 = slotR0 + 256;
    unsigned long long* slotW  = hx + ((size_t)dir * 32 + gbrow) * 256 + cg * 32 + gd;
    const size_t bufStride = (size_t)2 * B_ * H_;   // packets per parity

    for (int s = 0; s < tmax; ++s) {
        const int tt  = dir ? (tmax - 1 - s) : s;
        const int par = s & 1;

        // prefetch input projection for this step (independent of the poll)
        float pv0 = 0.f, pv1 = 0.f, pv2 = 0.f, pv3 = 0.f;
        if (tid < 64) {
            const float* pr = P + (size_t)(gbrow * T_ + tt) * G4_ + cg * 32 + gd;
            pv0 = pr[0]; pv1 = pr[256]; pv2 = pr[512]; pv3 = pr[768];
        }

        // poll h_{s-1} packets (tag >= s) for this lane's dim, both rows
        const size_t poff = (size_t)par * bufStride;
        unsigned long long pk0 = __hip_atomic_load(slotR0 + poff, __ATOMIC_RELAXED,
                                                   __HIP_MEMORY_SCOPE_AGENT);
        unsigned long long pk1 = __hip_atomic_load(slotR1 + poff, __ATOMIC_RELAXED,
                                                   __HIP_MEMORY_SCOPE_AGENT);
        while ((unsigned)(pk0 >> 32) < (unsigned)s) {
            __builtin_amdgcn_s_sleep(1);
            pk0 = __hip_atomic_load(slotR0 + poff, __ATOMIC_RELAXED,
                                    __HIP_MEMORY_SCOPE_AGENT);
        }
        while ((unsigned)(pk1 >> 32) < (unsigned)s) {
            __builtin_amdgcn_s_sleep(1);
            pk1 = __hip_atomic_load(slotR1 + poff, __ATOMIC_RELAXED,
                                    __HIP_MEMORY_SCOPE_AGENT);
        }
        const int h0u = (int)(unsigned)pk0;   // h[row0][q64+lane] bits
        const int h1u = (int)(unsigned)pk1;   // h[row1][q64+lane] bits

        // GEMV: 2 rows x 1 col, k in [64q, 64q+64); h via wave broadcast
        {
            float a0 = 0.f, a1 = 0.f;
#define STEPK(k) { \
            const float hs0 = __uint_as_float((unsigned)__builtin_amdgcn_readlane(h0u, k)); \
            const float hs1 = __uint_as_float((unsigned)__builtin_amdgcn_readlane(h1u, k)); \
            a0 = fmaf(hs0, wv[k], a0); \
            a1 = fmaf(hs1, wv[k], a1); }
            RPT64(STEPK)
#undef STEPK
            zp[par][q][0][cl] = a0;
            zp[par][q][1][cl] = a1;
        }
        __syncthreads();

        // gates + state update + h-packet publish (tag s+1, parity (s+1)&1)
        if (tid < 64) {
            float zi = pv0 + zp[par][0][gr][gd]      + zp[par][1][gr][gd]      + zp[par][2][gr][gd]      + zp[par][3][gr][gd];
            float zf = pv1 + zp[par][0][gr][32 + gd] + zp[par][1][gr][32 + gd] + zp[par][2][gr][32 + gd] + zp[par][3][gr][32 + gd];
            float zg = pv2 + zp[par][0][gr][64 + gd] + zp[par][1][gr][64 + gd] + zp[par][2][gr][64 + gd] + zp[par][3][gr][64 + gd];
            float zo = pv3 + zp[par][0][gr][96 + gd] + zp[par][1][gr][96 + gd] + zp[par][2][gr][96 + gd] + zp[par][3][gr][96 + gd];
            const float ig = 1.f / (1.f + expf(-zi));
            const float fg = 1.f / (1.f + expf(-zf));
            const float gg = tanhf(zg);
            const float og = 1.f / (1.f + expf(-zo));
            const float cn = fg * cst + ig * gg;
            const float hn = og * tanhf(cn);
            if (tt < glen) { cst = cn; hreg = hn; pacc += hn; }
            const unsigned long long opk =
                ((unsigned long long)(unsigned)(s + 1) << 32) |
                (unsigned long long)__float_as_uint(hreg);
            __hip_atomic_store(slotW + (size_t)((s + 1) & 1) * bufStride, opk,
                               __ATOMIC_RELAXED, __HIP_MEMORY_SCOPE_AGENT);
        }
        // no trailing barrier: zp[par] is next written at step s+2, which is
        // transitively ordered after this step's gate-read via the publish
        // chain (poll of tag s+2 requires team publishes of s+1, which
        // require every WG's waves -- covering all dims -- to have passed
        // this step's barrier and gate-read).
    }

    if (tid < 64)
        pool[gbrow * 512 + dir * 256 + cg * 32 + gd] = pacc / (float)glen;
}

// ---------------------------------------------------------------------------
// Kernel 4: fc_hidden = relu(pool @ Wfc + bfc); out = fc_hidden @ Wout + bout
// ---------------------------------------------------------------------------
__global__ __launch_bounds__(256)
void k_fc(const float* __restrict__ pool, const float* __restrict__ Wfc,
          const float* __restrict__ bfc, const float* __restrict__ Wout,
          const float* __restrict__ bout, float* __restrict__ out)
{
    __shared__ float p_sh[512];
    __shared__ float red[8];

    const int tid = threadIdx.x;
    const int b   = blockIdx.x;

    p_sh[tid]       = pool[b * 512 + tid];
    p_sh[256 + tid] = pool[b * 512 + 256 + tid];
    __syncthreads();

    float acc = bfc[tid];
#pragma unroll 8
    for (int k = 0; k < 512; ++k)
        acc += p_sh[k] * Wfc[(size_t)k * H_ + tid];
    const float fh = fmaxf(acc, 0.f);

    float p0 = fh * Wout[tid * 2 + 0];
    float p1 = fh * Wout[tid * 2 + 1];
#pragma unroll
    for (int off = 32; off > 0; off >>= 1) {
        p0 += __shfl_down(p0, off);
        p1 += __shfl_down(p1, off);
    }
    const int wave = tid >> 6;
    if ((tid & 63) == 0) { red[wave * 2] = p0; red[wave * 2 + 1] = p1; }
    __syncthreads();
    if (tid == 0) {
        out[b * 2 + 0] = red[0] + red[2] + red[4] + red[6] + bout[0];
        out[b * 2 + 1] = red[1] + red[3] + red[5] + red[7] + bout[1];
    }
}

__global__ void k_sentinel(float* out, int n)
{
    const int i = blockIdx.x * blockDim.x + threadIdx.x;
    if (i < n) out[i] = 1.0e9f;
}

extern "C" void kernel_launch(void* const* d_in, const int* in_sizes, int n_in,
                              void* d_out, int out_size, void* d_ws, size_t ws_size,
                              hipStream_t stream)
{
    const float* emb  = (const float*)d_in[0];
    const float* Win  = (const float*)d_in[1];
    const float* bin  = (const float*)d_in[2];
    const float* Wihf = (const float*)d_in[3];
    const float* Whhf = (const float*)d_in[4];
    const float* blf  = (const float*)d_in[5];
    const float* Wihb = (const float*)d_in[6];
    const float* Whhb = (const float*)d_in[7];
    const float* blb  = (const float*)d_in[8];
    const float* Wfc  = (const float*)d_in[9];
    const float* bfc  = (const float*)d_in[10];
    const float* Wout = (const float*)d_in[11];
    const float* bout = (const float*)d_in[12];
    const int*   x    = (const int*)d_in[13];
    const int*   lens = (const int*)d_in[15];
    float*       out  = (float*)d_out;

    const size_t need = ((size_t)M_ * H_ + 2 * (size_t)M_ * G4_) * sizeof(float);
    if (ws_size < need) {
        hipLaunchKernelGGL(k_sentinel, dim3(1), dim3(64), 0, stream, out, out_size);
        return;
    }

    float* z  = (float*)d_ws;                    // [16384,256] (dead after k2)
    float* Pf = z + (size_t)M_ * H_;             // [16384,1024]
    float* Pb = Pf + (size_t)M_ * G4_;           // [16384,1024]

    // overlay inside z region (init runs after k2 has consumed z)
    unsigned long long* hx   = (unsigned long long*)d_ws;        // packets
    float*              pool = (float*)(hx + HXN);               // [32][512]

    hipLaunchKernelGGL(k_embed_proj, dim3(2, 128), dim3(256), 0, stream,
                       emb, Win, bin, x, z);
    hipLaunchKernelGGL(k_in_proj, dim3(8, 128, 2), dim3(256), 0, stream,
                       z, Wihf, blf, Wihb, blb, Pf, Pb);
    hipLaunchKernelGGL(k_init, dim3(128), dim3(256), 0, stream, hx);
    hipLaunchKernelGGL(k_lstm_persist, dim3(NWG), dim3(THR), 0, stream,
                       Pf, Pb, Whhf, Whhb, lens, hx, pool);
    hipLaunchKernelGGL(k_fc, dim3(32), dim3(256), 0, stream,
                       pool, Wfc, bfc, Wout, bout, out);
}

// Round 2
// 1367.105 us; speedup vs baseline: 1.2631x; 1.2631x over previous
//
#include <hip/hip_runtime.h>
#include <math.h>

#define B_    32
#define T_    512
#define WDIM_ 300
#define H_    256
#define G4_   1024            // 4*H
#define M_    (B_ * T_)       // 16384

// persistent-LSTM geometry: team = 8 WGs covering one (dir, batch-pair)
#define NCG   8               // col groups per team (32 d's each)
#define NWG   256             // 2 dirs * 16 batch-pairs * NCG
#define THR   512
#define HXN   (2 * 2 * B_ * H_)   // packets: [buf][dir][32][256]

// repeat macros -> compile-time-constant indices (SROA-safe register arrays)
#define RPT4(M, b)  M(b) M((b)+1) M((b)+2) M((b)+3)
#define RPT16(M, b) RPT4(M, b) RPT4(M, (b)+4) RPT4(M, (b)+8) RPT4(M, (b)+12)
#define RPT64(M)    RPT16(M, 0) RPT16(M, 16) RPT16(M, 32) RPT16(M, 48)

// ---------------------------------------------------------------------------
// Kernel 1: z = relu(emb[x] @ W_in + b_in)   [16384,300]@[300,256]
// ---------------------------------------------------------------------------
__global__ __launch_bounds__(256)
void k_embed_proj(const float* __restrict__ emb, const float* __restrict__ Win,
                  const float* __restrict__ bin, const int* __restrict__ x,
                  float* __restrict__ z)
{
    __shared__ float Ash[16][132];
    __shared__ float Bsh[16][132];
    __shared__ int   rows[128];

    const int tid = threadIdx.x;
    const int tx = tid & 15, ty = tid >> 4;
    const int rm = blockIdx.y * 128;
    const int cn = blockIdx.x * 128;

    if (tid < 128) rows[tid] = x[rm + tid];
    __syncthreads();

    float acc[8][8];
#pragma unroll
    for (int i = 0; i < 8; ++i)
#pragma unroll
        for (int j = 0; j < 8; ++j) acc[i][j] = 0.f;

    for (int kc = 0; kc < 19; ++kc) {
        const int k0 = kc * 16;
#pragma unroll
        for (int e = 0; e < 8; ++e) {
            const int idx = e * 256 + tid;
            const int r = idx >> 4, kk = idx & 15;
            const int k = k0 + kk;
            const int v = rows[r];
            Ash[kk][r] = (k < WDIM_) ? emb[(size_t)v * WDIM_ + k] : 0.f;
        }
#pragma unroll
        for (int e = 0; e < 8; ++e) {
            const int idx = e * 256 + tid;
            const int kk = idx >> 7, n = idx & 127;
            const int k = k0 + kk;
            Bsh[kk][n] = (k < WDIM_) ? Win[(size_t)k * H_ + cn + n] : 0.f;
        }
        __syncthreads();
#pragma unroll
        for (int kk = 0; kk < 16; ++kk) {
            float a[8], bb[8];
#pragma unroll
            for (int i = 0; i < 8; ++i) a[i] = Ash[kk][ty * 8 + i];
#pragma unroll
            for (int j = 0; j < 8; ++j) bb[j] = Bsh[kk][tx * 8 + j];
#pragma unroll
            for (int i = 0; i < 8; ++i)
#pragma unroll
                for (int j = 0; j < 8; ++j) acc[i][j] += a[i] * bb[j];
        }
        __syncthreads();
    }

#pragma unroll
    for (int i = 0; i < 8; ++i) {
        const int row = rm + ty * 8 + i;
#pragma unroll
        for (int j = 0; j < 8; ++j) {
            const int col = cn + tx * 8 + j;
            z[(size_t)row * H_ + col] = fmaxf(acc[i][j] + bin[col], 0.f);
        }
    }
}

// ---------------------------------------------------------------------------
// Kernel 2: P_d = z @ Wih_d + bl_d  (both directions via blockIdx.z)
// ---------------------------------------------------------------------------
__global__ __launch_bounds__(256)
void k_in_proj(const float* __restrict__ z,
               const float* __restrict__ Wf, const float* __restrict__ blf,
               const float* __restrict__ Wb, const float* __restrict__ blb,
               float* __restrict__ Pf, float* __restrict__ Pb)
{
    const float* W  = blockIdx.z ? Wb  : Wf;
    const float* bl = blockIdx.z ? blb : blf;
    float*       P  = blockIdx.z ? Pb  : Pf;

    __shared__ float Ash[16][132];
    __shared__ float Bsh[16][132];

    const int tid = threadIdx.x;
    const int tx = tid & 15, ty = tid >> 4;
    const int rm = blockIdx.y * 128;
    const int cn = blockIdx.x * 128;

    float acc[8][8];
#pragma unroll
    for (int i = 0; i < 8; ++i)
#pragma unroll
        for (int j = 0; j < 8; ++j) acc[i][j] = 0.f;

    for (int kc = 0; kc < 16; ++kc) {
        const int k0 = kc * 16;
#pragma unroll
        for (int e = 0; e < 8; ++e) {
            const int idx = e * 256 + tid;
            const int r = idx >> 4, kk = idx & 15;
            Ash[kk][r] = z[(size_t)(rm + r) * H_ + k0 + kk];
        }
#pragma unroll
        for (int e = 0; e < 8; ++e) {
            const int idx = e * 256 + tid;
            const int kk = idx >> 7, n = idx & 127;
            Bsh[kk][n] = W[(size_t)(k0 + kk) * G4_ + cn + n];
        }
        __syncthreads();
#pragma unroll
        for (int kk = 0; kk < 16; ++kk) {
            float a[8], bb[8];
#pragma unroll
            for (int i = 0; i < 8; ++i) a[i] = Ash[kk][ty * 8 + i];
#pragma unroll
            for (int j = 0; j < 8; ++j) bb[j] = Bsh[kk][tx * 8 + j];
#pragma unroll
            for (int i = 0; i < 8; ++i)
#pragma unroll
                for (int j = 0; j < 8; ++j) acc[i][j] += a[i] * bb[j];
        }
        __syncthreads();
    }

#pragma unroll
    for (int i = 0; i < 8; ++i) {
        const int row = rm + ty * 8 + i;
#pragma unroll
        for (int j = 0; j < 8; ++j) {
            const int col = cn + tx * 8 + j;
            P[(size_t)row * G4_ + col] = acc[i][j] + bl[col];
        }
    }
}

// ---------------------------------------------------------------------------
// Init: zero h packet buffers ({h=0, tag=0} == initial state)
// ---------------------------------------------------------------------------
__global__ void k_init(unsigned long long* __restrict__ hx)
{
    const int i = blockIdx.x * blockDim.x + threadIdx.x;
    if (i < HXN) hx[i] = 0ull;
}

// ---------------------------------------------------------------------------
// Kernel 3: persistent bidirectional LSTM recurrence, fence-free.
// WG = (dir, batch-pair bg, colgroup cg of 32 d's). Team = 8 colgroups.
// h published as {h,tag} 8-byte relaxed agent-scope atomic packets, double-
// buffered by step parity; readers poll tag>=s. Teammates are blockIdx
// stride-32 -> same XCD slot -> exchange stays in one L2.
//
// v3: identical arithmetic/structure to the 920us v1, with ONE fix: the
// Whh slice wv[64] is pinned into VGPRs with an opaque asm touch. v1/v2
// reported VGPR_Count=64/56 -- too small to hold wv[64]+staging, proving
// the compiler was re-fetching Whh from L2 EVERY STEP (128KB/CU/step ~=
// 0.93us/step/XCD, exactly the unexplained ~2800cy/step stall; invisible
// in FETCH_SIZE because Whh L2-fits). After the asm, the values are
// opaque -> no remat, must stay register-resident (~100 VGPR, still
// 2 WG/CU capacity at 512 thr).
// ---------------------------------------------------------------------------
__global__ __launch_bounds__(THR, 2)
void k_lstm_persist(const float* __restrict__ Pf, const float* __restrict__ Pb,
                    const float* __restrict__ Whf, const float* __restrict__ Whb,
                    const int* __restrict__ lengths,
                    unsigned long long* __restrict__ hx,
                    float* __restrict__ pool)
{
    __shared__ float h_sh[2][256];
    __shared__ float zp[4][2][128];   // [ksplit][row][local gate-col]

    const int tid = threadIdx.x;
    const int wg  = blockIdx.x;
    const int bg  = wg & 15;
    const int dir = (wg >> 4) & 1;
    const int cg  = wg >> 5;          // 0..7

    const float* P   = dir ? Pb  : Pf;
    const float* Whh = dir ? Whb : Whf;

    const int brow0 = bg * 2;
    const int len0 = lengths[brow0], len1 = lengths[brow0 + 1];
    const int tmax = max(len0, len1);

    // GEMV mapping: q = k-quarter, cl = local col in [0,128)
    const int q   = tid >> 7;
    const int cl  = tid & 127;
    const int g0  = cl >> 5;
    const int dd0 = cl & 31;
    const int gcol = g0 * 256 + cg * 32 + dd0;    // global column
    const int q64 = q * 64;

    // persistent W slice: 64 floats (constant indices only!)
    float wv[64];
    {
        const float* wp = Whh + (size_t)q64 * G4_ + gcol;
#define LOADW(k) wv[k] = wp[(size_t)(k) * G4_];
        RPT64(LOADW)
#undef LOADW
    }
    // Pin wv into VGPRs: opaque to the compiler -> cannot rematerialize the
    // global loads inside the step loop, cannot demote to scratch reloads.
#define PINW(k) asm volatile("" : "+v"(wv[k]));
    RPT64(PINW)
#undef PINW

    // gate mapping (tid < 64): row gr, local hidden index gd
    const int gr    = tid >> 5;
    const int gd    = tid & 31;
    const int gbrow = brow0 + gr;
    const int glen  = gr ? len1 : len0;
    float cst = 0.f, hreg = 0.f, pacc = 0.f;

    // h-packet loader mapping (all 512 threads): row lrow, index ld
    const int lrow = tid >> 8;
    const int ld   = tid & 255;
    unsigned long long* slotR = hx + ((size_t)dir * 32 + brow0 + lrow) * 256 + ld;
    unsigned long long* slotW = hx + ((size_t)dir * 32 + gbrow) * 256 + cg * 32 + gd;
    const size_t bufStride = (size_t)2 * B_ * H_;   // packets per parity

    for (int s = 0; s < tmax; ++s) {
        const int tt = dir ? (tmax - 1 - s) : s;

        // prefetch input projection for this step (independent of the poll)
        float pv0 = 0.f, pv1 = 0.f, pv2 = 0.f, pv3 = 0.f;
        if (tid < 64) {
            const float* pr = P + (size_t)(gbrow * T_ + tt) * G4_ + cg * 32 + gd;
            pv0 = pr[0]; pv1 = pr[256]; pv2 = pr[512]; pv3 = pr[768];
        }

        // poll h_{s-1} packets (tag s) and stage into LDS
        {
            const unsigned long long* sp = slotR + (size_t)(s & 1) * bufStride;
            unsigned long long pk = __hip_atomic_load(sp, __ATOMIC_RELAXED,
                                                      __HIP_MEMORY_SCOPE_AGENT);
            while ((unsigned)(pk >> 32) < (unsigned)s) {
                __builtin_amdgcn_s_sleep(1);
                pk = __hip_atomic_load(sp, __ATOMIC_RELAXED,
                                       __HIP_MEMORY_SCOPE_AGENT);
            }
            h_sh[lrow][ld] = __uint_as_float((unsigned)pk);
        }
        __syncthreads();

        // GEMV: 2 rows x 1 col over k in [64q, 64q+64)
        {
            const float* h0 = &h_sh[0][q64];
            const float* h1 = &h_sh[1][q64];
            float a0 = 0.f, a1 = 0.f;
#define GEMV4(k4) { \
            const float4 hv0 = *(const float4*)(h0 + 4 * (k4)); \
            const float4 hv1 = *(const float4*)(h1 + 4 * (k4)); \
            a0 += hv0.x * wv[4*(k4)  ]; a1 += hv1.x * wv[4*(k4)  ]; \
            a0 += hv0.y * wv[4*(k4)+1]; a1 += hv1.y * wv[4*(k4)+1]; \
            a0 += hv0.z * wv[4*(k4)+2]; a1 += hv1.z * wv[4*(k4)+2]; \
            a0 += hv0.w * wv[4*(k4)+3]; a1 += hv1.w * wv[4*(k4)+3]; }
            RPT16(GEMV4, 0)
#undef GEMV4
            zp[q][0][cl] = a0;
            zp[q][1][cl] = a1;
        }
        __syncthreads();

        // gates + state update + h-packet publish (tag s+1, parity (s+1)&1)
        if (tid < 64) {
            float zi = pv0 + zp[0][gr][gd]      + zp[1][gr][gd]      + zp[2][gr][gd]      + zp[3][gr][gd];
            float zf = pv1 + zp[0][gr][32 + gd] + zp[1][gr][32 + gd] + zp[2][gr][32 + gd] + zp[3][gr][32 + gd];
            float zg = pv2 + zp[0][gr][64 + gd] + zp[1][gr][64 + gd] + zp[2][gr][64 + gd] + zp[3][gr][64 + gd];
            float zo = pv3 + zp[0][gr][96 + gd] + zp[1][gr][96 + gd] + zp[2][gr][96 + gd] + zp[3][gr][96 + gd];
            const float ig = 1.f / (1.f + expf(-zi));
            const float fg = 1.f / (1.f + expf(-zf));
            const float gg = tanhf(zg);
            const float og = 1.f / (1.f + expf(-zo));
            const float cn = fg * cst + ig * gg;
            const float hn = og * tanhf(cn);
            if (tt < glen) { cst = cn; hreg = hn; pacc += hn; }
            const unsigned long long opk =
                ((unsigned long long)(unsigned)(s + 1) << 32) |
                (unsigned long long)__float_as_uint(hreg);
            __hip_atomic_store(slotW + (size_t)((s + 1) & 1) * bufStride, opk,
                               __ATOMIC_RELAXED, __HIP_MEMORY_SCOPE_AGENT);
        }
        // no trailing barrier: zp of step s+1 is written only after the next
        // post-poll __syncthreads, which gate threads reach after this block.
    }

    if (tid < 64)
        pool[gbrow * 512 + dir * 256 + cg * 32 + gd] = pacc / (float)glen;
}

// ---------------------------------------------------------------------------
// Kernel 4: fc_hidden = relu(pool @ Wfc + bfc); out = fc_hidden @ Wout + bout
// ---------------------------------------------------------------------------
__global__ __launch_bounds__(256)
void k_fc(const float* __restrict__ pool, const float* __restrict__ Wfc,
          const float* __restrict__ bfc, const float* __restrict__ Wout,
          const float* __restrict__ bout, float* __restrict__ out)
{
    __shared__ float p_sh[512];
    __shared__ float red[8];

    const int tid = threadIdx.x;
    const int b   = blockIdx.x;

    p_sh[tid]       = pool[b * 512 + tid];
    p_sh[256 + tid] = pool[b * 512 + 256 + tid];
    __syncthreads();

    float acc = bfc[tid];
#pragma unroll 8
    for (int k = 0; k < 512; ++k)
        acc += p_sh[k] * Wfc[(size_t)k * H_ + tid];
    const float fh = fmaxf(acc, 0.f);

    float p0 = fh * Wout[tid * 2 + 0];
    float p1 = fh * Wout[tid * 2 + 1];
#pragma unroll
    for (int off = 32; off > 0; off >>= 1) {
        p0 += __shfl_down(p0, off);
        p1 += __shfl_down(p1, off);
    }
    const int wave = tid >> 6;
    if ((tid & 63) == 0) { red[wave * 2] = p0; red[wave * 2 + 1] = p1; }
    __syncthreads();
    if (tid == 0) {
        out[b * 2 + 0] = red[0] + red[2] + red[4] + red[6] + bout[0];
        out[b * 2 + 1] = red[1] + red[3] + red[5] + red[7] + bout[1];
    }
}

__global__ void k_sentinel(float* out, int n)
{
    const int i = blockIdx.x * blockDim.x + threadIdx.x;
    if (i < n) out[i] = 1.0e9f;
}

extern "C" void kernel_launch(void* const* d_in, const int* in_sizes, int n_in,
                              void* d_out, int out_size, void* d_ws, size_t ws_size,
                              hipStream_t stream)
{
    const float* emb  = (const float*)d_in[0];
    const float* Win  = (const float*)d_in[1];
    const float* bin  = (const float*)d_in[2];
    const float* Wihf = (const float*)d_in[3];
    const float* Whhf = (const float*)d_in[4];
    const float* blf  = (const float*)d_in[5];
    const float* Wihb = (const float*)d_in[6];
    const float* Whhb = (const float*)d_in[7];
    const float* blb  = (const float*)d_in[8];
    const float* Wfc  = (const float*)d_in[9];
    const float* bfc  = (const float*)d_in[10];
    const float* Wout = (const float*)d_in[11];
    const float* bout = (const float*)d_in[12];
    const int*   x    = (const int*)d_in[13];
    const int*   lens = (const int*)d_in[15];
    float*       out  = (float*)d_out;

    const size_t need = ((size_t)M_ * H_ + 2 * (size_t)M_ * G4_) * sizeof(float);
    if (ws_size < need) {
        hipLaunchKernelGGL(k_sentinel, dim3(1), dim3(64), 0, stream, out, out_size);
        return;
    }

    float* z  = (float*)d_ws;                    // [16384,256] (dead after k2)
    float* Pf = z + (size_t)M_ * H_;             // [16384,1024]
    float* Pb = Pf + (size_t)M_ * G4_;           // [16384,1024]

    // overlay inside z region (init runs after k2 has consumed z)
    unsigned long long* hx   = (unsigned long long*)d_ws;        // packets
    float*              pool = (float*)(hx + HXN);               // [32][512]

    hipLaunchKernelGGL(k_embed_proj, dim3(2, 128), dim3(256), 0, stream,
                       emb, Win, bin, x, z);
    hipLaunchKernelGGL(k_in_proj, dim3(8, 128, 2), dim3(256), 0, stream,
                       z, Wihf, blf, Wihb, blb, Pf, Pb);
    hipLaunchKernelGGL(k_init, dim3(128), dim3(256), 0, stream, hx);
    hipLaunchKernelGGL(k_lstm_persist, dim3(NWG), dim3(THR), 0, stream,
                       Pf, Pb, Whhf, Whhb, lens, hx, pool);
    hipLaunchKernelGGL(k_fc, dim3(32), dim3(256), 0, stream,
                       pool, Wfc, bfc, Wout, bout, out);
}